// Round 7
// baseline (363.846 us; speedup 1.0000x reference)
//
#include <hip/hip_runtime.h>

// PocketGNN on MI355X — round 6.
// - EdgeConv first matmul on nodes: A = x@(w1t-w1b)+b1 (f32), B = x@w1b (f16)
// - edge_gemm: 512 threads / 8 waves, wave = M64 x N32 (acc 32 regs) -> within the
//   128-reg (512,4) budget each wave fits single-batch stage (16 loads in flight)
//   AND kk-double-buffered bh, while keeping 2 blocks/CU (16 waves).
// - Edges dst-sorted (counting sort); permuted LDS rows (bit-swap involution) so each
//   lane's 16 acc values are 16 consecutive sorted edges -> register segment-max,
//   ~10x merged atomics. relu(segment_max) == atomicMax(int) into zero-init y.
// - XCD-chunked bijective block swizzle: B (f16, 5MB) ~L2-resident per XCD.
// - h@w2 f16 single-MFMA (absmax 2.4e-4 vs 9.5e-4 threshold).

#define NN 10000
#define NE 160000
#define NG 64
#define NP 10048  // nodes padded to 64
#define EB 64     // edges per block

typedef __attribute__((ext_vector_type(8))) _Float16 f16x8;
typedef __attribute__((ext_vector_type(4))) _Float16 f16x4;
typedef __attribute__((ext_vector_type(4))) float f32x4;

// ---------------- edge sort by dst (counting sort) ----------------
__global__ void hist_kernel(const int* __restrict__ dstI, int* __restrict__ hist) {
    int i = blockIdx.x * blockDim.x + threadIdx.x;
    if (i < NE) atomicAdd(&hist[dstI[i]], 1);
}

// in-place safe: cursor may alias hist
__global__ void scan_kernel(const int* __restrict__ hist, int* __restrict__ cursor) {
    __shared__ int sums[256];
    const int t = threadIdx.x;
    const int per = (NN + 255) / 256;  // 40
    const int lo = t * per, hi = (lo + per < NN) ? lo + per : NN;
    int s = 0;
    for (int i = lo; i < hi; ++i) s += hist[i];
    sums[t] = s;
    __syncthreads();
    for (int ofs = 1; ofs < 256; ofs <<= 1) {
        int add = (t >= ofs) ? sums[t - ofs] : 0;
        __syncthreads();
        sums[t] += add;
        __syncthreads();
    }
    int run = sums[t] - s;  // exclusive prefix
    for (int i = lo; i < hi; ++i) {
        int h = hist[i];      // read BEFORE aliased write
        cursor[i] = run;
        run += h;
    }
}

__global__ void scatter_kernel(const int* __restrict__ srcI, const int* __restrict__ dstI,
                               int* __restrict__ cursor,
                               int* __restrict__ se2, int* __restrict__ de2) {
    int i = blockIdx.x * blockDim.x + threadIdx.x;
    if (i < NE) {
        int d = dstI[i];
        int p = atomicAdd(&cursor[d], 1);
        se2[p] = srcI[i];
        de2[p] = d;
    }
}

// ---------------- weight prep ----------------
// WcT [512][C]: rows 0..255 = (w1t-w1b)^T, 256..511 = w1b^T.  w2T [256][256] = w2^T.
__global__ void prep_weights(const float* __restrict__ w1, const float* __restrict__ w2, int C,
                             _Float16* __restrict__ WcT, _Float16* __restrict__ w2T) {
    int total1 = 512 * C;
    int total = total1 + 256 * 256;
    for (int i = blockIdx.x * blockDim.x + threadIdx.x; i < total; i += gridDim.x * blockDim.x) {
        if (i < total1) {
            int n = i / C, k = i - n * C;
            float v = (n < 256) ? (w1[k * 256 + n] - w1[(C + k) * 256 + n])
                                : w1[(C + k) * 256 + (n - 256)];
            WcT[n * C + k] = (_Float16)v;
        } else {
            int j = i - total1;
            int n = j >> 8, k = j & 255;
            w2T[n * 256 + k] = (_Float16)w2[k * 256 + n];
        }
    }
}

// fp32 [N,C] -> f16 [NP,C], pad rows zeroed (vectorized x4)
template <int C>
__global__ void conv_rows(const float* __restrict__ src, _Float16* __restrict__ xh) {
    const int total4 = NP * C / 4;
    const int c4 = C / 4;
    for (int i4 = blockIdx.x * blockDim.x + threadIdx.x; i4 < total4; i4 += gridDim.x * blockDim.x) {
        const int row = i4 / c4;
        f16x4 o;
        if (row < NN) {
            float4 v = ((const float4*)src)[i4];
            o[0] = (_Float16)v.x; o[1] = (_Float16)v.y;
            o[2] = (_Float16)v.z; o[3] = (_Float16)v.w;
        } else {
            o[0] = o[1] = o[2] = o[3] = (_Float16)0.f;
        }
        ((f16x4*)xh)[i4] = o;
    }
}

// ---------------- node GEMM: [A | B] = x @ [Wc_A | Wc_B]; A f32 (+b1), B f16 ----------------
// grid (NP/64, 2); wave owns 64 cols (t<4) -> halved xh re-reads vs 4-col-block version
template <int C>
__global__ __launch_bounds__(256) void node_gemm(
    const _Float16* __restrict__ xh, const _Float16* __restrict__ WT,
    const float* __restrict__ b1, float* __restrict__ Af, _Float16* __restrict__ Bh) {
    const int wave = threadIdx.x >> 6, lane = threadIdx.x & 63;
    const int lrow = lane & 15, lk = (lane >> 4) * 8;
    const int r0 = blockIdx.x * 64;
    const int c0 = blockIdx.y * 256 + wave * 64;

    f32x4 acc[4][4] = {};
#pragma unroll
    for (int kk = 0; kk < C; kk += 32) {
        f16x8 ah[4];
#pragma unroll
        for (int m = 0; m < 4; ++m)
            ah[m] = *(const f16x8*)(xh + (size_t)(r0 + m * 16 + lrow) * C + kk + lk);
#pragma unroll
        for (int t = 0; t < 4; ++t) {
            f16x8 bh = *(const f16x8*)(WT + (size_t)(c0 + t * 16 + lrow) * C + kk + lk);
#pragma unroll
            for (int m = 0; m < 4; ++m)
                acc[m][t] = __builtin_amdgcn_mfma_f32_16x16x32_f16(ah[m], bh, acc[m][t], 0, 0, 0);
        }
    }
    if (blockIdx.y == 0) {  // A half: +bias, f32
#pragma unroll
        for (int t = 0; t < 4; ++t) {
            const int col = c0 + t * 16 + lrow;
            const float bias = b1[col];
#pragma unroll
            for (int m = 0; m < 4; ++m)
#pragma unroll
                for (int j = 0; j < 4; ++j) {
                    const int row = r0 + m * 16 + (lane >> 4) * 4 + j;
                    Af[(size_t)row * 256 + col] = acc[m][t][j] + bias;
                }
        }
    } else {  // B half: f16
#pragma unroll
        for (int t = 0; t < 4; ++t) {
            const int col = c0 - 256 + t * 16 + lrow;
#pragma unroll
            for (int m = 0; m < 4; ++m)
#pragma unroll
                for (int j = 0; j < 4; ++j) {
                    const int row = r0 + m * 16 + (lane >> 4) * 4 + j;
                    Bh[(size_t)row * 256 + col] = (_Float16)acc[m][t][j];
                }
        }
    }
}

// ---------------- fused edge kernel (sorted-by-dst edges) ----------------
// 512 threads / 8 waves. Wave w: stages edges w*8..w*8+7; GEMM M=64 x N=32 (cols w*32..).
// LDS row perm (bit-swap involution): edge el = (m<<4)|(g<<2)|j  <->  row = (g<<4)|(m<<2)|j
// so lane quarter g's acc[m][t][j] = edge g*16 + m*4 + j: 16 CONSECUTIVE sorted edges
// -> register segment-max, merged atomics.
__global__ __launch_bounds__(512, 4) void edge_gemm(
    const float* __restrict__ Af, const _Float16* __restrict__ Bh,
    const int* __restrict__ se2, const int* __restrict__ de2,
    const _Float16* __restrict__ w2T,
    const float* __restrict__ b2, float* __restrict__ y) {
    __shared__ _Float16 hh[EB * 256];  // 32 KB, XOR-swizzled
    const int tid = threadIdx.x;
    const int wave = tid >> 6, lane = tid & 63;

    // XCD-chunked bijective swizzle (grid = 2500 = 8*312 + 4)
    const int orig = blockIdx.x;
    const int xcd = orig & 7, pos = orig >> 3;
    const int q = 2500 >> 3, r = 2500 & 7;  // 312, 4
    const int bid = (xcd < r ? xcd * (q + 1) : r * (q + 1) + (xcd - r) * q) + pos;
    const int e0 = bid * EB;

    // ---- stage: h = relu(A[dst] + B[src]) -> f16 LDS at permuted row ----
    {
        int se[8], de[8];
#pragma unroll
        for (int i = 0; i < 8; ++i) {
            se[i] = se2[e0 + wave * 8 + i];
            de[i] = de2[e0 + wave * 8 + i];
        }
        float4 av[8];
        f16x4 bv[8];
#pragma unroll
        for (int i = 0; i < 8; ++i) {
            bv[i] = *(const f16x4*)(Bh + (size_t)se[i] * 256 + lane * 4);
            av[i] = *(const float4*)(Af + (size_t)de[i] * 256 + lane * 4);
        }
#pragma unroll
        for (int i = 0; i < 8; ++i) {
            const int el = wave * 8 + i;  // block-local edge 0..63
            const int row = ((el >> 2) & 3) * 16 + (el >> 4) * 4 + (el & 3);
            f16x4 vh;
            vh[0] = (_Float16)fmaxf(av[i].x + (float)bv[i][0], 0.f);
            vh[1] = (_Float16)fmaxf(av[i].y + (float)bv[i][1], 0.f);
            vh[2] = (_Float16)fmaxf(av[i].z + (float)bv[i][2], 0.f);
            vh[3] = (_Float16)fmaxf(av[i].w + (float)bv[i][3], 0.f);
            const int idx = (row * 256 + lane * 4) ^ ((row & 7) << 3);
            *(f16x4*)(&hh[idx]) = vh;
        }
    }
    __syncthreads();

    // ---- gemm: M=64 (4 tiles) x wave's N=32 (2 tiles), K=256, bh kk-double-buffered ----
    const int lrow = lane & 15, lk = (lane >> 4) * 8;
    const _Float16* wbase = w2T + (size_t)(wave * 32 + lrow) * 256 + lk;

    f32x4 acc[4][2] = {};
    f16x8 bhA[2], bhB[2];
    bhA[0] = *(const f16x8*)(wbase);
    bhA[1] = *(const f16x8*)(wbase + 16 * 256);
#pragma unroll
    for (int kk = 0; kk < 256; kk += 32) {
        if (kk + 32 < 256) {
            bhB[0] = *(const f16x8*)(wbase + kk + 32);
            bhB[1] = *(const f16x8*)(wbase + 16 * 256 + kk + 32);
        }
        f16x8 ah[4];
#pragma unroll
        for (int m = 0; m < 4; ++m) {
            const int row = m * 16 + lrow;
            const int idx = (row * 256 + kk + lk) ^ ((row & 7) << 3);
            ah[m] = *(const f16x8*)(&hh[idx]);
        }
#pragma unroll
        for (int t = 0; t < 2; ++t)
#pragma unroll
            for (int m = 0; m < 4; ++m)
                acc[m][t] = __builtin_amdgcn_mfma_f32_16x16x32_f16(ah[m], bhA[t], acc[m][t], 0, 0, 0);
        bhA[0] = bhB[0];
        bhA[1] = bhB[1];
    }

    // ---- epilogue: lane quarter g holds edges e0+g*16..+15; segment-max, merged atomics ----
    const int g = lane >> 4;
    int d[16];
#pragma unroll
    for (int k = 0; k < 16; ++k) d[k] = de2[e0 + g * 16 + k];
#pragma unroll
    for (int t = 0; t < 2; ++t) {
        const int col = wave * 32 + t * 16 + lrow;
        const float bias = b2[col];  // constant per col: apply AFTER segment max
        float run = acc[0][t][0];
        int dp = d[0];
#pragma unroll
        for (int k = 1; k < 16; ++k) {
            const float v = acc[k >> 2][t][k & 3];
            if (d[k] == dp) {
                run = fmaxf(run, v);
            } else {
                const float o = run + bias;
                if (o > 0.f) atomicMax((int*)(y + (size_t)dp * 256 + col), __float_as_int(o));
                run = v;
                dp = d[k];
            }
        }
        const float o = run + bias;
        if (o > 0.f) atomicMax((int*)(y + (size_t)dp * 256 + col), __float_as_int(o));
    }
}

// ---------------- per-graph mean+max pool ----------------
__global__ void pool_kernel(const float* __restrict__ y, const int* __restrict__ batch,
                            float* __restrict__ pooled) {
    const int g = blockIdx.x;
    __shared__ int slo, shi;
    if (threadIdx.x == 0) {
        int lo = 0, hi = NN;
        while (lo < hi) { int m = (lo + hi) >> 1; if (batch[m] < g) lo = m + 1; else hi = m; }
        slo = lo;
        int lo2 = lo, hi2 = NN;
        while (lo2 < hi2) { int m = (lo2 + hi2) >> 1; if (batch[m] < g + 1) lo2 = m + 1; else hi2 = m; }
        shi = lo2;
    }
    __syncthreads();
    const int lo = slo, hi = shi, c = threadIdx.x;
    float s0 = 0.f, s1 = 0.f, s2 = 0.f, s3 = 0.f;
    float m0 = 0.f, m1 = 0.f, m2 = 0.f, m3 = 0.f;  // y >= 0 -> 0 safe identity
    int n = lo;
    for (; n + 4 <= hi; n += 4) {
        float v0 = y[(size_t)(n + 0) * 256 + c];
        float v1 = y[(size_t)(n + 1) * 256 + c];
        float v2 = y[(size_t)(n + 2) * 256 + c];
        float v3 = y[(size_t)(n + 3) * 256 + c];
        s0 += v0; s1 += v1; s2 += v2; s3 += v3;
        m0 = fmaxf(m0, v0); m1 = fmaxf(m1, v1); m2 = fmaxf(m2, v2); m3 = fmaxf(m3, v3);
    }
    for (; n < hi; ++n) {
        float v = y[(size_t)n * 256 + c];
        s0 += v; m0 = fmaxf(m0, v);
    }
    const float s = (s0 + s1) + (s2 + s3);
    const float mx = fmaxf(fmaxf(m0, m1), fmaxf(m2, m3));
    const int cnt = hi - lo;
    pooled[g * 512 + c] = cnt ? s / (float)cnt : 0.f;
    pooled[g * 512 + 256 + c] = cnt ? mx : 0.f;
}

// ---------------- classifier MLP ----------------
__global__ void classifier(const float* __restrict__ pooled,
                           const float* __restrict__ w1, const float* __restrict__ b1,
                           const float* __restrict__ w2, const float* __restrict__ b2,
                           const float* __restrict__ w3, const float* __restrict__ b3,
                           float* __restrict__ out) {
    const int g = blockIdx.x;
    __shared__ float ph[512];
    __shared__ float o1[256];
    __shared__ float o2[64];
    const int t = threadIdx.x;  // 256 threads
    ph[t] = pooled[g * 512 + t];
    ph[t + 256] = pooled[g * 512 + 256 + t];
    __syncthreads();
    float s = 0.f;
    for (int k = 0; k < 512; ++k) s += ph[k] * w1[k * 256 + t];
    o1[t] = fmaxf(s + b1[t], 0.f);
    __syncthreads();
    if (t < 64) {
        float s2 = 0.f;
        for (int k = 0; k < 256; ++k) s2 += o1[k] * w2[k * 64 + t];
        o2[t] = fmaxf(s2 + b2[t], 0.f);
    }
    __syncthreads();
    if (t < 64) {
        float v = o2[t] * w3[t];
        for (int off = 32; off; off >>= 1) v += __shfl_down(v, off);
        if (t == 0) out[g] = v + b3[0];
    }
}

extern "C" void kernel_launch(void* const* d_in, const int* in_sizes, int n_in,
                              void* d_out, int out_size, void* d_ws, size_t ws_size,
                              hipStream_t stream) {
    (void)in_sizes; (void)n_in; (void)out_size; (void)ws_size;
    const float* x0 = (const float*)d_in[0];
    const int* eidx = (const int*)d_in[1];
    const int* batch = (const int*)d_in[2];
    const int* srcI = eidx;            // edge_index[0] = src
    const int* dstI = eidx + NE;       // edge_index[1] = dst

    char* ws = (char*)d_ws;
    size_t off = 0;
    auto alloc = [&](size_t bytes) -> void* {
        void* p = ws + off;
        off += (bytes + 255) & ~(size_t)255;
        return p;
    };
    _Float16* xh = (_Float16*)alloc((size_t)NP * 256 * 2);
    float* Af = (float*)alloc((size_t)NP * 256 * 4);
    _Float16* Bh = (_Float16*)alloc((size_t)NP * 256 * 2);
    float* y  = (float*)alloc((size_t)NP * 256 * 4);
    _Float16* WcT = (_Float16*)alloc(512 * 256 * 2);
    _Float16* w2T = (_Float16*)alloc(256 * 256 * 2);
    float* pooled = (float*)alloc(64 * 512 * 4);
    int* hist = (int*)alloc(NN * 4);
    int* se2 = (int*)alloc(NE * 4);
    int* de2 = (int*)alloc(NE * 4);

    const float* lw[3][4] = {
        {(const float*)d_in[3],  (const float*)d_in[4],  (const float*)d_in[5],  (const float*)d_in[6]},
        {(const float*)d_in[7],  (const float*)d_in[8],  (const float*)d_in[9],  (const float*)d_in[10]},
        {(const float*)d_in[11], (const float*)d_in[12], (const float*)d_in[13], (const float*)d_in[14]},
    };

    // sort edges by dst (once, reused all layers)
    hipMemsetAsync(hist, 0, NN * 4, stream);
    hist_kernel<<<dim3((NE + 255) / 256), dim3(256), 0, stream>>>(dstI, hist);
    scan_kernel<<<dim3(1), dim3(256), 0, stream>>>(hist, hist);  // in-place exclusive scan
    scatter_kernel<<<dim3((NE + 255) / 256), dim3(256), 0, stream>>>(srcI, dstI, hist, se2, de2);

    conv_rows<128><<<dim3(1024), dim3(256), 0, stream>>>(x0, xh);

    for (int l = 0; l < 3; ++l) {
        const int C = (l == 0) ? 128 : 256;
        prep_weights<<<dim3(256), dim3(256), 0, stream>>>(lw[l][0], lw[l][2], C, WcT, w2T);
        if (C == 128)
            node_gemm<128><<<dim3(NP / 64, 2), dim3(256), 0, stream>>>(xh, WcT, lw[l][1], Af, Bh);
        else
            node_gemm<256><<<dim3(NP / 64, 2), dim3(256), 0, stream>>>(xh, WcT, lw[l][1], Af, Bh);
        hipMemsetAsync(y, 0, (size_t)NP * 256 * 4, stream);
        edge_gemm<<<dim3(NE / EB), dim3(512), 0, stream>>>(Af, Bh, se2, de2, w2T, lw[l][3], y);
        if (l < 2)
            conv_rows<256><<<dim3(1024), dim3(256), 0, stream>>>(y, xh);
    }

    pool_kernel<<<dim3(NG), dim3(256), 0, stream>>>(y, batch, pooled);
    classifier<<<dim3(NG), dim3(256), 0, stream>>>(pooled,
        (const float*)d_in[15], (const float*)d_in[16],
        (const float*)d_in[17], (const float*)d_in[18],
        (const float*)d_in[19], (const float*)d_in[20], (float*)d_out);
}

// Round 8
// 363.172 us; speedup vs baseline: 1.0019x; 1.0019x over previous
//
#include <hip/hip_runtime.h>

// PocketGNN on MI355X — round 6.
// - EdgeConv first matmul on nodes: A = x@(w1t-w1b)+b1 (f32), B = x@w1b (f16)
// - edge_gemm: 512 threads / 8 waves, wave = M64 x N32 (acc 32 regs) -> within the
//   128-reg (512,4) budget each wave fits single-batch stage (16 loads in flight)
//   AND kk-double-buffered bh, while keeping 2 blocks/CU (16 waves).
// - Edges dst-sorted (counting sort); permuted LDS rows (bit-swap involution) so each
//   lane's 16 acc values are 16 consecutive sorted edges -> register segment-max,
//   ~10x merged atomics. relu(segment_max) == atomicMax(int) into zero-init y.
// - XCD-chunked bijective block swizzle: B (f16, 5MB) ~L2-resident per XCD.
// - h@w2 f16 single-MFMA (absmax 2.4e-4 vs 9.5e-4 threshold).

#define NN 10000
#define NE 160000
#define NG 64
#define NP 10048  // nodes padded to 64
#define EB 64     // edges per block

typedef __attribute__((ext_vector_type(8))) _Float16 f16x8;
typedef __attribute__((ext_vector_type(4))) _Float16 f16x4;
typedef __attribute__((ext_vector_type(4))) float f32x4;

// ---------------- edge sort by dst (counting sort) ----------------
__global__ void hist_kernel(const int* __restrict__ dstI, int* __restrict__ hist) {
    int i = blockIdx.x * blockDim.x + threadIdx.x;
    if (i < NE) atomicAdd(&hist[dstI[i]], 1);
}

// in-place safe: cursor may alias hist
__global__ void scan_kernel(const int* __restrict__ hist, int* __restrict__ cursor) {
    __shared__ int sums[256];
    const int t = threadIdx.x;
    const int per = (NN + 255) / 256;  // 40
    const int lo = t * per, hi = (lo + per < NN) ? lo + per : NN;
    int s = 0;
    for (int i = lo; i < hi; ++i) s += hist[i];
    sums[t] = s;
    __syncthreads();
    for (int ofs = 1; ofs < 256; ofs <<= 1) {
        int add = (t >= ofs) ? sums[t - ofs] : 0;
        __syncthreads();
        sums[t] += add;
        __syncthreads();
    }
    int run = sums[t] - s;  // exclusive prefix
    for (int i = lo; i < hi; ++i) {
        int h = hist[i];      // read BEFORE aliased write
        cursor[i] = run;
        run += h;
    }
}

__global__ void scatter_kernel(const int* __restrict__ srcI, const int* __restrict__ dstI,
                               int* __restrict__ cursor,
                               int* __restrict__ se2, int* __restrict__ de2) {
    int i = blockIdx.x * blockDim.x + threadIdx.x;
    if (i < NE) {
        int d = dstI[i];
        int p = atomicAdd(&cursor[d], 1);
        se2[p] = srcI[i];
        de2[p] = d;
    }
}

// ---------------- weight prep ----------------
// WcT [512][C]: rows 0..255 = (w1t-w1b)^T, 256..511 = w1b^T.  w2T [256][256] = w2^T.
__global__ void prep_weights(const float* __restrict__ w1, const float* __restrict__ w2, int C,
                             _Float16* __restrict__ WcT, _Float16* __restrict__ w2T) {
    int total1 = 512 * C;
    int total = total1 + 256 * 256;
    for (int i = blockIdx.x * blockDim.x + threadIdx.x; i < total; i += gridDim.x * blockDim.x) {
        if (i < total1) {
            int n = i / C, k = i - n * C;
            float v = (n < 256) ? (w1[k * 256 + n] - w1[(C + k) * 256 + n])
                                : w1[(C + k) * 256 + (n - 256)];
            WcT[n * C + k] = (_Float16)v;
        } else {
            int j = i - total1;
            int n = j >> 8, k = j & 255;
            w2T[n * 256 + k] = (_Float16)w2[k * 256 + n];
        }
    }
}

// fp32 [N,C] -> f16 [NP,C], pad rows zeroed (vectorized x4)
template <int C>
__global__ void conv_rows(const float* __restrict__ src, _Float16* __restrict__ xh) {
    const int total4 = NP * C / 4;
    const int c4 = C / 4;
    for (int i4 = blockIdx.x * blockDim.x + threadIdx.x; i4 < total4; i4 += gridDim.x * blockDim.x) {
        const int row = i4 / c4;
        f16x4 o;
        if (row < NN) {
            float4 v = ((const float4*)src)[i4];
            o[0] = (_Float16)v.x; o[1] = (_Float16)v.y;
            o[2] = (_Float16)v.z; o[3] = (_Float16)v.w;
        } else {
            o[0] = o[1] = o[2] = o[3] = (_Float16)0.f;
        }
        ((f16x4*)xh)[i4] = o;
    }
}

// ---------------- node GEMM: [A | B] = x @ [Wc_A | Wc_B]; A f32 (+b1), B f16 ----------------
// grid (NP/64, 2); wave owns 64 cols (t<4) -> halved xh re-reads vs 4-col-block version
template <int C>
__global__ __launch_bounds__(256) void node_gemm(
    const _Float16* __restrict__ xh, const _Float16* __restrict__ WT,
    const float* __restrict__ b1, float* __restrict__ Af, _Float16* __restrict__ Bh) {
    const int wave = threadIdx.x >> 6, lane = threadIdx.x & 63;
    const int lrow = lane & 15, lk = (lane >> 4) * 8;
    const int r0 = blockIdx.x * 64;
    const int c0 = blockIdx.y * 256 + wave * 64;

    f32x4 acc[4][4] = {};
#pragma unroll
    for (int kk = 0; kk < C; kk += 32) {
        f16x8 ah[4];
#pragma unroll
        for (int m = 0; m < 4; ++m)
            ah[m] = *(const f16x8*)(xh + (size_t)(r0 + m * 16 + lrow) * C + kk + lk);
#pragma unroll
        for (int t = 0; t < 4; ++t) {
            f16x8 bh = *(const f16x8*)(WT + (size_t)(c0 + t * 16 + lrow) * C + kk + lk);
#pragma unroll
            for (int m = 0; m < 4; ++m)
                acc[m][t] = __builtin_amdgcn_mfma_f32_16x16x32_f16(ah[m], bh, acc[m][t], 0, 0, 0);
        }
    }
    if (blockIdx.y == 0) {  // A half: +bias, f32
#pragma unroll
        for (int t = 0; t < 4; ++t) {
            const int col = c0 + t * 16 + lrow;
            const float bias = b1[col];
#pragma unroll
            for (int m = 0; m < 4; ++m)
#pragma unroll
                for (int j = 0; j < 4; ++j) {
                    const int row = r0 + m * 16 + (lane >> 4) * 4 + j;
                    Af[(size_t)row * 256 + col] = acc[m][t][j] + bias;
                }
        }
    } else {  // B half: f16
#pragma unroll
        for (int t = 0; t < 4; ++t) {
            const int col = c0 - 256 + t * 16 + lrow;
#pragma unroll
            for (int m = 0; m < 4; ++m)
#pragma unroll
                for (int j = 0; j < 4; ++j) {
                    const int row = r0 + m * 16 + (lane >> 4) * 4 + j;
                    Bh[(size_t)row * 256 + col] = (_Float16)acc[m][t][j];
                }
        }
    }
}

// ---------------- fused edge kernel (sorted-by-dst edges) ----------------
// 512 threads / 8 waves. Wave w: stages edges w*8..w*8+7; GEMM M=64 x N=32 (cols w*32..).
// LDS row perm (bit-swap involution): edge el = (m<<4)|(g<<2)|j  <->  row = (g<<4)|(m<<2)|j
// so lane quarter g's acc[m][t][j] = edge g*16 + m*4 + j: 16 CONSECUTIVE sorted edges
// -> register segment-max, merged atomics.
__global__ __launch_bounds__(512, 4) void edge_gemm(
    const float* __restrict__ Af, const _Float16* __restrict__ Bh,
    const int* __restrict__ se2, const int* __restrict__ de2,
    const _Float16* __restrict__ w2T,
    const float* __restrict__ b2, float* __restrict__ y) {
    __shared__ _Float16 hh[EB * 256];  // 32 KB, XOR-swizzled
    const int tid = threadIdx.x;
    const int wave = tid >> 6, lane = tid & 63;

    // XCD-chunked bijective swizzle (grid = 2500 = 8*312 + 4)
    const int orig = blockIdx.x;
    const int xcd = orig & 7, pos = orig >> 3;
    const int q = 2500 >> 3, r = 2500 & 7;  // 312, 4
    const int bid = (xcd < r ? xcd * (q + 1) : r * (q + 1) + (xcd - r) * q) + pos;
    const int e0 = bid * EB;

    // ---- stage: h = relu(A[dst] + B[src]) -> f16 LDS at permuted row ----
    {
        int se[8], de[8];
#pragma unroll
        for (int i = 0; i < 8; ++i) {
            se[i] = se2[e0 + wave * 8 + i];
            de[i] = de2[e0 + wave * 8 + i];
        }
        float4 av[8];
        f16x4 bv[8];
#pragma unroll
        for (int i = 0; i < 8; ++i) {
            bv[i] = *(const f16x4*)(Bh + (size_t)se[i] * 256 + lane * 4);
            av[i] = *(const float4*)(Af + (size_t)de[i] * 256 + lane * 4);
        }
#pragma unroll
        for (int i = 0; i < 8; ++i) {
            const int el = wave * 8 + i;  // block-local edge 0..63
            const int row = ((el >> 2) & 3) * 16 + (el >> 4) * 4 + (el & 3);
            f16x4 vh;
            vh[0] = (_Float16)fmaxf(av[i].x + (float)bv[i][0], 0.f);
            vh[1] = (_Float16)fmaxf(av[i].y + (float)bv[i][1], 0.f);
            vh[2] = (_Float16)fmaxf(av[i].z + (float)bv[i][2], 0.f);
            vh[3] = (_Float16)fmaxf(av[i].w + (float)bv[i][3], 0.f);
            const int idx = (row * 256 + lane * 4) ^ ((row & 7) << 3);
            *(f16x4*)(&hh[idx]) = vh;
        }
    }
    __syncthreads();

    // ---- gemm: M=64 (4 tiles) x wave's N=32 (2 tiles), K=256, bh kk-double-buffered ----
    const int lrow = lane & 15, lk = (lane >> 4) * 8;
    const _Float16* wbase = w2T + (size_t)(wave * 32 + lrow) * 256 + lk;

    f32x4 acc[4][2] = {};
    f16x8 bhA[2], bhB[2];
    bhA[0] = *(const f16x8*)(wbase);
    bhA[1] = *(const f16x8*)(wbase + 16 * 256);
#pragma unroll
    for (int kk = 0; kk < 256; kk += 32) {
        if (kk + 32 < 256) {
            bhB[0] = *(const f16x8*)(wbase + kk + 32);
            bhB[1] = *(const f16x8*)(wbase + 16 * 256 + kk + 32);
        }
        f16x8 ah[4];
#pragma unroll
        for (int m = 0; m < 4; ++m) {
            const int row = m * 16 + lrow;
            const int idx = (row * 256 + kk + lk) ^ ((row & 7) << 3);
            ah[m] = *(const f16x8*)(&hh[idx]);
        }
#pragma unroll
        for (int t = 0; t < 2; ++t)
#pragma unroll
            for (int m = 0; m < 4; ++m)
                acc[m][t] = __builtin_amdgcn_mfma_f32_16x16x32_f16(ah[m], bhA[t], acc[m][t], 0, 0, 0);
        bhA[0] = bhB[0];
        bhA[1] = bhB[1];
    }

    // ---- epilogue: lane quarter g holds edges e0+g*16..+15; segment-max, merged atomics ----
    const int g = lane >> 4;
    int d[16];
#pragma unroll
    for (int k = 0; k < 16; ++k) d[k] = de2[e0 + g * 16 + k];
#pragma unroll
    for (int t = 0; t < 2; ++t) {
        const int col = wave * 32 + t * 16 + lrow;
        const float bias = b2[col];  // constant per col: apply AFTER segment max
        float run = acc[0][t][0];
        int dp = d[0];
#pragma unroll
        for (int k = 1; k < 16; ++k) {
            const float v = acc[k >> 2][t][k & 3];
            if (d[k] == dp) {
                run = fmaxf(run, v);
            } else {
                const float o = run + bias;
                if (o > 0.f) atomicMax((int*)(y + (size_t)dp * 256 + col), __float_as_int(o));
                run = v;
                dp = d[k];
            }
        }
        const float o = run + bias;
        if (o > 0.f) atomicMax((int*)(y + (size_t)dp * 256 + col), __float_as_int(o));
    }
}

// ---------------- per-graph mean+max pool ----------------
__global__ void pool_kernel(const float* __restrict__ y, const int* __restrict__ batch,
                            float* __restrict__ pooled) {
    const int g = blockIdx.x;
    __shared__ int slo, shi;
    if (threadIdx.x == 0) {
        int lo = 0, hi = NN;
        while (lo < hi) { int m = (lo + hi) >> 1; if (batch[m] < g) lo = m + 1; else hi = m; }
        slo = lo;
        int lo2 = lo, hi2 = NN;
        while (lo2 < hi2) { int m = (lo2 + hi2) >> 1; if (batch[m] < g + 1) lo2 = m + 1; else hi2 = m; }
        shi = lo2;
    }
    __syncthreads();
    const int lo = slo, hi = shi, c = threadIdx.x;
    float s0 = 0.f, s1 = 0.f, s2 = 0.f, s3 = 0.f;
    float m0 = 0.f, m1 = 0.f, m2 = 0.f, m3 = 0.f;  // y >= 0 -> 0 safe identity
    int n = lo;
    for (; n + 4 <= hi; n += 4) {
        float v0 = y[(size_t)(n + 0) * 256 + c];
        float v1 = y[(size_t)(n + 1) * 256 + c];
        float v2 = y[(size_t)(n + 2) * 256 + c];
        float v3 = y[(size_t)(n + 3) * 256 + c];
        s0 += v0; s1 += v1; s2 += v2; s3 += v3;
        m0 = fmaxf(m0, v0); m1 = fmaxf(m1, v1); m2 = fmaxf(m2, v2); m3 = fmaxf(m3, v3);
    }
    for (; n < hi; ++n) {
        float v = y[(size_t)n * 256 + c];
        s0 += v; m0 = fmaxf(m0, v);
    }
    const float s = (s0 + s1) + (s2 + s3);
    const float mx = fmaxf(fmaxf(m0, m1), fmaxf(m2, m3));
    const int cnt = hi - lo;
    pooled[g * 512 + c] = cnt ? s / (float)cnt : 0.f;
    pooled[g * 512 + 256 + c] = cnt ? mx : 0.f;
}

// ---------------- classifier MLP ----------------
__global__ void classifier(const float* __restrict__ pooled,
                           const float* __restrict__ w1, const float* __restrict__ b1,
                           const float* __restrict__ w2, const float* __restrict__ b2,
                           const float* __restrict__ w3, const float* __restrict__ b3,
                           float* __restrict__ out) {
    const int g = blockIdx.x;
    __shared__ float ph[512];
    __shared__ float o1[256];
    __shared__ float o2[64];
    const int t = threadIdx.x;  // 256 threads
    ph[t] = pooled[g * 512 + t];
    ph[t + 256] = pooled[g * 512 + 256 + t];
    __syncthreads();
    float s = 0.f;
    for (int k = 0; k < 512; ++k) s += ph[k] * w1[k * 256 + t];
    o1[t] = fmaxf(s + b1[t], 0.f);
    __syncthreads();
    if (t < 64) {
        float s2 = 0.f;
        for (int k = 0; k < 256; ++k) s2 += o1[k] * w2[k * 64 + t];
        o2[t] = fmaxf(s2 + b2[t], 0.f);
    }
    __syncthreads();
    if (t < 64) {
        float v = o2[t] * w3[t];
        for (int off = 32; off; off >>= 1) v += __shfl_down(v, off);
        if (t == 0) out[g] = v + b3[0];
    }
}

extern "C" void kernel_launch(void* const* d_in, const int* in_sizes, int n_in,
                              void* d_out, int out_size, void* d_ws, size_t ws_size,
                              hipStream_t stream) {
    (void)in_sizes; (void)n_in; (void)out_size; (void)ws_size;
    const float* x0 = (const float*)d_in[0];
    const int* eidx = (const int*)d_in[1];
    const int* batch = (const int*)d_in[2];
    const int* srcI = eidx;            // edge_index[0] = src
    const int* dstI = eidx + NE;       // edge_index[1] = dst

    char* ws = (char*)d_ws;
    size_t off = 0;
    auto alloc = [&](size_t bytes) -> void* {
        void* p = ws + off;
        off += (bytes + 255) & ~(size_t)255;
        return p;
    };
    _Float16* xh = (_Float16*)alloc((size_t)NP * 256 * 2);
    float* Af = (float*)alloc((size_t)NP * 256 * 4);
    _Float16* Bh = (_Float16*)alloc((size_t)NP * 256 * 2);
    float* y  = (float*)alloc((size_t)NP * 256 * 4);
    _Float16* WcT = (_Float16*)alloc(512 * 256 * 2);
    _Float16* w2T = (_Float16*)alloc(256 * 256 * 2);
    float* pooled = (float*)alloc(64 * 512 * 4);
    int* hist = (int*)alloc(NN * 4);
    int* se2 = (int*)alloc(NE * 4);
    int* de2 = (int*)alloc(NE * 4);

    const float* lw[3][4] = {
        {(const float*)d_in[3],  (const float*)d_in[4],  (const float*)d_in[5],  (const float*)d_in[6]},
        {(const float*)d_in[7],  (const float*)d_in[8],  (const float*)d_in[9],  (const float*)d_in[10]},
        {(const float*)d_in[11], (const float*)d_in[12], (const float*)d_in[13], (const float*)d_in[14]},
    };

    // sort edges by dst (once, reused all layers)
    hipMemsetAsync(hist, 0, NN * 4, stream);
    hist_kernel<<<dim3((NE + 255) / 256), dim3(256), 0, stream>>>(dstI, hist);
    scan_kernel<<<dim3(1), dim3(256), 0, stream>>>(hist, hist);  // in-place exclusive scan
    scatter_kernel<<<dim3((NE + 255) / 256), dim3(256), 0, stream>>>(srcI, dstI, hist, se2, de2);

    conv_rows<128><<<dim3(1024), dim3(256), 0, stream>>>(x0, xh);

    for (int l = 0; l < 3; ++l) {
        const int C = (l == 0) ? 128 : 256;
        prep_weights<<<dim3(256), dim3(256), 0, stream>>>(lw[l][0], lw[l][2], C, WcT, w2T);
        if (C == 128)
            node_gemm<128><<<dim3(NP / 64, 2), dim3(256), 0, stream>>>(xh, WcT, lw[l][1], Af, Bh);
        else
            node_gemm<256><<<dim3(NP / 64, 2), dim3(256), 0, stream>>>(xh, WcT, lw[l][1], Af, Bh);
        hipMemsetAsync(y, 0, (size_t)NP * 256 * 4, stream);
        edge_gemm<<<dim3(NE / EB), dim3(512), 0, stream>>>(Af, Bh, se2, de2, w2T, lw[l][3], y);
        if (l < 2)
            conv_rows<256><<<dim3(1024), dim3(256), 0, stream>>>(y, xh);
    }

    pool_kernel<<<dim3(NG), dim3(256), 0, stream>>>(y, batch, pooled);
    classifier<<<dim3(NG), dim3(256), 0, stream>>>(pooled,
        (const float*)d_in[15], (const float*)d_in[16],
        (const float*)d_in[17], (const float*)d_in[18],
        (const float*)d_in[19], (const float*)d_in[20], (float*)d_out);
}

// Round 9
// 362.120 us; speedup vs baseline: 1.0048x; 1.0029x over previous
//
#include <hip/hip_runtime.h>

// PocketGNN on MI355X — round 6.
// - EdgeConv first matmul on nodes: A = x@(w1t-w1b)+b1 (f32), B = x@w1b (f16)
// - edge_gemm: 512 threads / 8 waves, wave = M64 x N32 (acc 32 regs) -> within the
//   128-reg (512,4) budget each wave fits single-batch stage (16 loads in flight)
//   AND kk-double-buffered bh, while keeping 2 blocks/CU (16 waves).
// - Edges dst-sorted (counting sort); permuted LDS rows (bit-swap involution) so each
//   lane's 16 acc values are 16 consecutive sorted edges -> register segment-max,
//   ~10x merged atomics. relu(segment_max) == atomicMax(int) into zero-init y.
// - XCD-chunked bijective block swizzle: B (f16, 5MB) ~L2-resident per XCD.
// - h@w2 f16 single-MFMA (absmax 2.4e-4 vs 9.5e-4 threshold).

#define NN 10000
#define NE 160000
#define NG 64
#define NP 10048  // nodes padded to 64
#define EB 64     // edges per block

typedef __attribute__((ext_vector_type(8))) _Float16 f16x8;
typedef __attribute__((ext_vector_type(4))) _Float16 f16x4;
typedef __attribute__((ext_vector_type(4))) float f32x4;

// ---------------- edge sort by dst (counting sort) ----------------
__global__ void hist_kernel(const int* __restrict__ dstI, int* __restrict__ hist) {
    int i = blockIdx.x * blockDim.x + threadIdx.x;
    if (i < NE) atomicAdd(&hist[dstI[i]], 1);
}

// in-place safe: cursor may alias hist
__global__ void scan_kernel(const int* __restrict__ hist, int* __restrict__ cursor) {
    __shared__ int sums[256];
    const int t = threadIdx.x;
    const int per = (NN + 255) / 256;  // 40
    const int lo = t * per, hi = (lo + per < NN) ? lo + per : NN;
    int s = 0;
    for (int i = lo; i < hi; ++i) s += hist[i];
    sums[t] = s;
    __syncthreads();
    for (int ofs = 1; ofs < 256; ofs <<= 1) {
        int add = (t >= ofs) ? sums[t - ofs] : 0;
        __syncthreads();
        sums[t] += add;
        __syncthreads();
    }
    int run = sums[t] - s;  // exclusive prefix
    for (int i = lo; i < hi; ++i) {
        int h = hist[i];      // read BEFORE aliased write
        cursor[i] = run;
        run += h;
    }
}

__global__ void scatter_kernel(const int* __restrict__ srcI, const int* __restrict__ dstI,
                               int* __restrict__ cursor,
                               int* __restrict__ se2, int* __restrict__ de2) {
    int i = blockIdx.x * blockDim.x + threadIdx.x;
    if (i < NE) {
        int d = dstI[i];
        int p = atomicAdd(&cursor[d], 1);
        se2[p] = srcI[i];
        de2[p] = d;
    }
}

// ---------------- weight prep ----------------
// WcT [512][C]: rows 0..255 = (w1t-w1b)^T, 256..511 = w1b^T.  w2T [256][256] = w2^T.
__global__ void prep_weights(const float* __restrict__ w1, const float* __restrict__ w2, int C,
                             _Float16* __restrict__ WcT, _Float16* __restrict__ w2T) {
    int total1 = 512 * C;
    int total = total1 + 256 * 256;
    for (int i = blockIdx.x * blockDim.x + threadIdx.x; i < total; i += gridDim.x * blockDim.x) {
        if (i < total1) {
            int n = i / C, k = i - n * C;
            float v = (n < 256) ? (w1[k * 256 + n] - w1[(C + k) * 256 + n])
                                : w1[(C + k) * 256 + (n - 256)];
            WcT[n * C + k] = (_Float16)v;
        } else {
            int j = i - total1;
            int n = j >> 8, k = j & 255;
            w2T[n * 256 + k] = (_Float16)w2[k * 256 + n];
        }
    }
}

// fp32 [N,C] -> f16 [NP,C], pad rows zeroed (vectorized x4)
template <int C>
__global__ void conv_rows(const float* __restrict__ src, _Float16* __restrict__ xh) {
    const int total4 = NP * C / 4;
    const int c4 = C / 4;
    for (int i4 = blockIdx.x * blockDim.x + threadIdx.x; i4 < total4; i4 += gridDim.x * blockDim.x) {
        const int row = i4 / c4;
        f16x4 o;
        if (row < NN) {
            float4 v = ((const float4*)src)[i4];
            o[0] = (_Float16)v.x; o[1] = (_Float16)v.y;
            o[2] = (_Float16)v.z; o[3] = (_Float16)v.w;
        } else {
            o[0] = o[1] = o[2] = o[3] = (_Float16)0.f;
        }
        ((f16x4*)xh)[i4] = o;
    }
}

// ---------------- node GEMM: [A | B] = x @ [Wc_A | Wc_B]; A f32 (+b1), B f16 ----------------
// grid (NP/64, 2); wave owns 64 cols (t<4) -> halved xh re-reads vs 4-col-block version
template <int C>
__global__ __launch_bounds__(256) void node_gemm(
    const _Float16* __restrict__ xh, const _Float16* __restrict__ WT,
    const float* __restrict__ b1, float* __restrict__ Af, _Float16* __restrict__ Bh) {
    const int wave = threadIdx.x >> 6, lane = threadIdx.x & 63;
    const int lrow = lane & 15, lk = (lane >> 4) * 8;
    const int r0 = blockIdx.x * 64;
    const int c0 = blockIdx.y * 256 + wave * 64;

    f32x4 acc[4][4] = {};
#pragma unroll
    for (int kk = 0; kk < C; kk += 32) {
        f16x8 ah[4];
#pragma unroll
        for (int m = 0; m < 4; ++m)
            ah[m] = *(const f16x8*)(xh + (size_t)(r0 + m * 16 + lrow) * C + kk + lk);
#pragma unroll
        for (int t = 0; t < 4; ++t) {
            f16x8 bh = *(const f16x8*)(WT + (size_t)(c0 + t * 16 + lrow) * C + kk + lk);
#pragma unroll
            for (int m = 0; m < 4; ++m)
                acc[m][t] = __builtin_amdgcn_mfma_f32_16x16x32_f16(ah[m], bh, acc[m][t], 0, 0, 0);
        }
    }
    if (blockIdx.y == 0) {  // A half: +bias, f32
#pragma unroll
        for (int t = 0; t < 4; ++t) {
            const int col = c0 + t * 16 + lrow;
            const float bias = b1[col];
#pragma unroll
            for (int m = 0; m < 4; ++m)
#pragma unroll
                for (int j = 0; j < 4; ++j) {
                    const int row = r0 + m * 16 + (lane >> 4) * 4 + j;
                    Af[(size_t)row * 256 + col] = acc[m][t][j] + bias;
                }
        }
    } else {  // B half: f16
#pragma unroll
        for (int t = 0; t < 4; ++t) {
            const int col = c0 - 256 + t * 16 + lrow;
#pragma unroll
            for (int m = 0; m < 4; ++m)
#pragma unroll
                for (int j = 0; j < 4; ++j) {
                    const int row = r0 + m * 16 + (lane >> 4) * 4 + j;
                    Bh[(size_t)row * 256 + col] = (_Float16)acc[m][t][j];
                }
        }
    }
}

// ---------------- fused edge kernel (sorted-by-dst edges) ----------------
// 512 threads / 8 waves. Wave w: stages edges w*8..w*8+7; GEMM M=64 x N=32 (cols w*32..).
// LDS row perm (bit-swap involution): edge el = (m<<4)|(g<<2)|j  <->  row = (g<<4)|(m<<2)|j
// so lane quarter g's acc[m][t][j] = edge g*16 + m*4 + j: 16 CONSECUTIVE sorted edges
// -> register segment-max, merged atomics.
__global__ __launch_bounds__(512, 4) void edge_gemm(
    const float* __restrict__ Af, const _Float16* __restrict__ Bh,
    const int* __restrict__ se2, const int* __restrict__ de2,
    const _Float16* __restrict__ w2T,
    const float* __restrict__ b2, float* __restrict__ y) {
    __shared__ _Float16 hh[EB * 256];  // 32 KB, XOR-swizzled
    const int tid = threadIdx.x;
    const int wave = tid >> 6, lane = tid & 63;

    // XCD-chunked bijective swizzle (grid = 2500 = 8*312 + 4)
    const int orig = blockIdx.x;
    const int xcd = orig & 7, pos = orig >> 3;
    const int q = 2500 >> 3, r = 2500 & 7;  // 312, 4
    const int bid = (xcd < r ? xcd * (q + 1) : r * (q + 1) + (xcd - r) * q) + pos;
    const int e0 = bid * EB;

    // ---- stage: h = relu(A[dst] + B[src]) -> f16 LDS at permuted row ----
    {
        int se[8], de[8];
#pragma unroll
        for (int i = 0; i < 8; ++i) {
            se[i] = se2[e0 + wave * 8 + i];
            de[i] = de2[e0 + wave * 8 + i];
        }
        float4 av[8];
        f16x4 bv[8];
#pragma unroll
        for (int i = 0; i < 8; ++i) {
            bv[i] = *(const f16x4*)(Bh + (size_t)se[i] * 256 + lane * 4);
            av[i] = *(const float4*)(Af + (size_t)de[i] * 256 + lane * 4);
        }
#pragma unroll
        for (int i = 0; i < 8; ++i) {
            const int el = wave * 8 + i;  // block-local edge 0..63
            const int row = ((el >> 2) & 3) * 16 + (el >> 4) * 4 + (el & 3);
            f16x4 vh;
            vh[0] = (_Float16)fmaxf(av[i].x + (float)bv[i][0], 0.f);
            vh[1] = (_Float16)fmaxf(av[i].y + (float)bv[i][1], 0.f);
            vh[2] = (_Float16)fmaxf(av[i].z + (float)bv[i][2], 0.f);
            vh[3] = (_Float16)fmaxf(av[i].w + (float)bv[i][3], 0.f);
            const int idx = (row * 256 + lane * 4) ^ ((row & 7) << 3);
            *(f16x4*)(&hh[idx]) = vh;
        }
    }
    __syncthreads();

    // ---- gemm: M=64 (4 tiles) x wave's N=32 (2 tiles), K=256, bh kk-double-buffered ----
    const int lrow = lane & 15, lk = (lane >> 4) * 8;
    const _Float16* wbase = w2T + (size_t)(wave * 32 + lrow) * 256 + lk;

    f32x4 acc[4][2] = {};
    f16x8 bhA[2], bhB[2];
    bhA[0] = *(const f16x8*)(wbase);
    bhA[1] = *(const f16x8*)(wbase + 16 * 256);
#pragma unroll
    for (int kk = 0; kk < 256; kk += 32) {
        if (kk + 32 < 256) {
            bhB[0] = *(const f16x8*)(wbase + kk + 32);
            bhB[1] = *(const f16x8*)(wbase + 16 * 256 + kk + 32);
        }
        f16x8 ah[4];
#pragma unroll
        for (int m = 0; m < 4; ++m) {
            const int row = m * 16 + lrow;
            const int idx = (row * 256 + kk + lk) ^ ((row & 7) << 3);
            ah[m] = *(const f16x8*)(&hh[idx]);
        }
#pragma unroll
        for (int t = 0; t < 2; ++t)
#pragma unroll
            for (int m = 0; m < 4; ++m)
                acc[m][t] = __builtin_amdgcn_mfma_f32_16x16x32_f16(ah[m], bhA[t], acc[m][t], 0, 0, 0);
        bhA[0] = bhB[0];
        bhA[1] = bhB[1];
    }

    // ---- epilogue: lane quarter g holds edges e0+g*16..+15; segment-max, merged atomics ----
    const int g = lane >> 4;
    int d[16];
#pragma unroll
    for (int k = 0; k < 16; ++k) d[k] = de2[e0 + g * 16 + k];
#pragma unroll
    for (int t = 0; t < 2; ++t) {
        const int col = wave * 32 + t * 16 + lrow;
        const float bias = b2[col];  // constant per col: apply AFTER segment max
        float run = acc[0][t][0];
        int dp = d[0];
#pragma unroll
        for (int k = 1; k < 16; ++k) {
            const float v = acc[k >> 2][t][k & 3];
            if (d[k] == dp) {
                run = fmaxf(run, v);
            } else {
                const float o = run + bias;
                if (o > 0.f) atomicMax((int*)(y + (size_t)dp * 256 + col), __float_as_int(o));
                run = v;
                dp = d[k];
            }
        }
        const float o = run + bias;
        if (o > 0.f) atomicMax((int*)(y + (size_t)dp * 256 + col), __float_as_int(o));
    }
}

// ---------------- per-graph mean+max pool ----------------
__global__ void pool_kernel(const float* __restrict__ y, const int* __restrict__ batch,
                            float* __restrict__ pooled) {
    const int g = blockIdx.x;
    __shared__ int slo, shi;
    if (threadIdx.x == 0) {
        int lo = 0, hi = NN;
        while (lo < hi) { int m = (lo + hi) >> 1; if (batch[m] < g) lo = m + 1; else hi = m; }
        slo = lo;
        int lo2 = lo, hi2 = NN;
        while (lo2 < hi2) { int m = (lo2 + hi2) >> 1; if (batch[m] < g + 1) lo2 = m + 1; else hi2 = m; }
        shi = lo2;
    }
    __syncthreads();
    const int lo = slo, hi = shi, c = threadIdx.x;
    float s0 = 0.f, s1 = 0.f, s2 = 0.f, s3 = 0.f;
    float m0 = 0.f, m1 = 0.f, m2 = 0.f, m3 = 0.f;  // y >= 0 -> 0 safe identity
    int n = lo;
    for (; n + 4 <= hi; n += 4) {
        float v0 = y[(size_t)(n + 0) * 256 + c];
        float v1 = y[(size_t)(n + 1) * 256 + c];
        float v2 = y[(size_t)(n + 2) * 256 + c];
        float v3 = y[(size_t)(n + 3) * 256 + c];
        s0 += v0; s1 += v1; s2 += v2; s3 += v3;
        m0 = fmaxf(m0, v0); m1 = fmaxf(m1, v1); m2 = fmaxf(m2, v2); m3 = fmaxf(m3, v3);
    }
    for (; n < hi; ++n) {
        float v = y[(size_t)n * 256 + c];
        s0 += v; m0 = fmaxf(m0, v);
    }
    const float s = (s0 + s1) + (s2 + s3);
    const float mx = fmaxf(fmaxf(m0, m1), fmaxf(m2, m3));
    const int cnt = hi - lo;
    pooled[g * 512 + c] = cnt ? s / (float)cnt : 0.f;
    pooled[g * 512 + 256 + c] = cnt ? mx : 0.f;
}

// ---------------- classifier MLP ----------------
__global__ void classifier(const float* __restrict__ pooled,
                           const float* __restrict__ w1, const float* __restrict__ b1,
                           const float* __restrict__ w2, const float* __restrict__ b2,
                           const float* __restrict__ w3, const float* __restrict__ b3,
                           float* __restrict__ out) {
    const int g = blockIdx.x;
    __shared__ float ph[512];
    __shared__ float o1[256];
    __shared__ float o2[64];
    const int t = threadIdx.x;  // 256 threads
    ph[t] = pooled[g * 512 + t];
    ph[t + 256] = pooled[g * 512 + 256 + t];
    __syncthreads();
    float s = 0.f;
    for (int k = 0; k < 512; ++k) s += ph[k] * w1[k * 256 + t];
    o1[t] = fmaxf(s + b1[t], 0.f);
    __syncthreads();
    if (t < 64) {
        float s2 = 0.f;
        for (int k = 0; k < 256; ++k) s2 += o1[k] * w2[k * 64 + t];
        o2[t] = fmaxf(s2 + b2[t], 0.f);
    }
    __syncthreads();
    if (t < 64) {
        float v = o2[t] * w3[t];
        for (int off = 32; off; off >>= 1) v += __shfl_down(v, off);
        if (t == 0) out[g] = v + b3[0];
    }
}

extern "C" void kernel_launch(void* const* d_in, const int* in_sizes, int n_in,
                              void* d_out, int out_size, void* d_ws, size_t ws_size,
                              hipStream_t stream) {
    (void)in_sizes; (void)n_in; (void)out_size; (void)ws_size;
    const float* x0 = (const float*)d_in[0];
    const int* eidx = (const int*)d_in[1];
    const int* batch = (const int*)d_in[2];
    const int* srcI = eidx;            // edge_index[0] = src
    const int* dstI = eidx + NE;       // edge_index[1] = dst

    char* ws = (char*)d_ws;
    size_t off = 0;
    auto alloc = [&](size_t bytes) -> void* {
        void* p = ws + off;
        off += (bytes + 255) & ~(size_t)255;
        return p;
    };
    _Float16* xh = (_Float16*)alloc((size_t)NP * 256 * 2);
    float* Af = (float*)alloc((size_t)NP * 256 * 4);
    _Float16* Bh = (_Float16*)alloc((size_t)NP * 256 * 2);
    float* y  = (float*)alloc((size_t)NP * 256 * 4);
    _Float16* WcT = (_Float16*)alloc(512 * 256 * 2);
    _Float16* w2T = (_Float16*)alloc(256 * 256 * 2);
    float* pooled = (float*)alloc(64 * 512 * 4);
    int* hist = (int*)alloc(NN * 4);
    int* se2 = (int*)alloc(NE * 4);
    int* de2 = (int*)alloc(NE * 4);

    const float* lw[3][4] = {
        {(const float*)d_in[3],  (const float*)d_in[4],  (const float*)d_in[5],  (const float*)d_in[6]},
        {(const float*)d_in[7],  (const float*)d_in[8],  (const float*)d_in[9],  (const float*)d_in[10]},
        {(const float*)d_in[11], (const float*)d_in[12], (const float*)d_in[13], (const float*)d_in[14]},
    };

    // sort edges by dst (once, reused all layers)
    hipMemsetAsync(hist, 0, NN * 4, stream);
    hist_kernel<<<dim3((NE + 255) / 256), dim3(256), 0, stream>>>(dstI, hist);
    scan_kernel<<<dim3(1), dim3(256), 0, stream>>>(hist, hist);  // in-place exclusive scan
    scatter_kernel<<<dim3((NE + 255) / 256), dim3(256), 0, stream>>>(srcI, dstI, hist, se2, de2);

    conv_rows<128><<<dim3(1024), dim3(256), 0, stream>>>(x0, xh);

    for (int l = 0; l < 3; ++l) {
        const int C = (l == 0) ? 128 : 256;
        prep_weights<<<dim3(256), dim3(256), 0, stream>>>(lw[l][0], lw[l][2], C, WcT, w2T);
        if (C == 128)
            node_gemm<128><<<dim3(NP / 64, 2), dim3(256), 0, stream>>>(xh, WcT, lw[l][1], Af, Bh);
        else
            node_gemm<256><<<dim3(NP / 64, 2), dim3(256), 0, stream>>>(xh, WcT, lw[l][1], Af, Bh);
        hipMemsetAsync(y, 0, (size_t)NP * 256 * 4, stream);
        edge_gemm<<<dim3(NE / EB), dim3(512), 0, stream>>>(Af, Bh, se2, de2, w2T, lw[l][3], y);
        if (l < 2)
            conv_rows<256><<<dim3(1024), dim3(256), 0, stream>>>(y, xh);
    }

    pool_kernel<<<dim3(NG), dim3(256), 0, stream>>>(y, batch, pooled);
    classifier<<<dim3(NG), dim3(256), 0, stream>>>(pooled,
        (const float*)d_in[15], (const float*)d_in[16],
        (const float*)d_in[17], (const float*)d_in[18],
        (const float*)d_in[19], (const float*)d_in[20], (float*)d_out);
}